// Round 13
// baseline (164.233 us; speedup 1.0000x reference)
//
#include <hip/hip_runtime.h>
#include <stdint.h>

#define Bsz 16384
#define Hh  512
#define Kd  1024      // I + H
#define BM  128       // M rows per workgroup
#define BNJ 32        // j columns per workgroup (x5 gates)
#define BK  32        // K per tile
#define NT  32        // K tiles

typedef __attribute__((ext_vector_type(8))) short bf16x8;
typedef __attribute__((ext_vector_type(4))) float f32x4;
typedef __attribute__((ext_vector_type(8))) unsigned short u16x8;

__device__ __forceinline__ unsigned short f2bf(float f) {
    union { float f; unsigned u; } v; v.f = f;
    unsigned u = v.u;
    return (unsigned short)((u + 0x7fffu + ((u >> 16) & 1u)) >> 16);
}
__device__ __forceinline__ float fast_tanh(float x) {
    float e = __expf(2.f * x);
    return (e - 1.f) / (e + 1.f);
}
__device__ __forceinline__ float fast_sigmoid(float x) {
    return 1.f / (1.f + __expf(-x));
}

// ---- pack A fragment-linear: unit blk = (mblk*32 + t)*8 + u  (1 KB units) ----
// elem blk*512 + l*8 + e = A[mblk*128 + u*16 + (l&15)][t*32 + (l>>4)*8 + e]
// where A[r][k] = x[r][k] (k<512) else h_prev[r][k-512]
__global__ void pack_A(const float* __restrict__ x, const float* __restrict__ h,
                       unsigned short* __restrict__ A) {
    const long total = (long)Bsz * Kd / 8;   // 2,097,152 units of 8
    for (long i = (long)blockIdx.x * blockDim.x + threadIdx.x; i < total;
         i += (long)gridDim.x * blockDim.x) {
        int  l    = (int)(i & 63);
        long blk  = i >> 6;
        int  u    = (int)(blk & 7);
        int  t    = (int)((blk >> 3) & 31);
        long mblk = blk >> 8;
        long row  = mblk * 128 + u * 16 + (l & 15);
        int  k0   = t * 32 + ((l >> 4) << 3);
        const float* src = (k0 < 512) ? (x + row * 512 + k0)
                                      : (h + row * 512 + (k0 - 512));
        float4 f0 = *(const float4*)(src);
        float4 f1 = *(const float4*)(src + 4);
        u16x8 o;
        o[0]=f2bf(f0.x); o[1]=f2bf(f0.y); o[2]=f2bf(f0.z); o[3]=f2bf(f0.w);
        o[4]=f2bf(f1.x); o[5]=f2bf(f1.y); o[6]=f2bf(f1.z); o[7]=f2bf(f1.w);
        *(u16x8*)(A + (i << 3)) = o;
    }
}

// ---- pack B into fragment-linear layout (unchanged, proven) ----
// elem addr = jgrp*81920 + g*16384 + kt*1024 + kh*512 + l*8 + e
//  = W[g][ j = jgrp*16 + (l&15) ][ k = kt*64 + kh*32 + (l>>4)*8 + e ]
// BK=32 tile T: unit base = jgrp*81920 + g*16384 + T*512 (elems)
__global__ void pack_B(const float* __restrict__ Wxi, const float* __restrict__ Whi,
                       const float* __restrict__ Wxf, const float* __restrict__ Whf,
                       const float* __restrict__ Wxc, const float* __restrict__ Whc,
                       const float* __restrict__ Wxo, const float* __restrict__ Who,
                       const float* __restrict__ We,
                       const float* __restrict__ bxi, const float* __restrict__ bhi,
                       const float* __restrict__ bxf, const float* __restrict__ bhf,
                       const float* __restrict__ bxc, const float* __restrict__ bhc,
                       const float* __restrict__ bxo, const float* __restrict__ bho,
                       const float* __restrict__ be,
                       unsigned short* __restrict__ Bp, float* __restrict__ bias) {
    const long id = (long)blockIdx.x * blockDim.x + threadIdx.x;  // 327680 total
    if (id < 327680) {
        int blk = (int)(id >> 6);
        int l   = (int)(id & 63);
        int kh  = blk & 1;
        int kt  = (blk >> 1) & 15;
        int rest = blk >> 5;
        int g    = rest % 5;
        int jgrp = rest / 5;
        int j  = jgrp * 16 + (l & 15);
        int k0 = kt * 64 + kh * 32 + ((l >> 4) << 3);
        const float* src;
        if (g == 4) {
            src = We + (long)j * 1024 + k0;
        } else {
            const float* Wx = (g == 0) ? Wxi : (g == 1) ? Wxf : (g == 2) ? Wxc : Wxo;
            const float* Wh = (g == 0) ? Whi : (g == 1) ? Whf : (g == 2) ? Whc : Who;
            src = (k0 < 512) ? (Wx + (long)j * 512 + k0)
                             : (Wh + (long)j * 512 + (k0 - 512));
        }
        float4 f0 = *(const float4*)(src);
        float4 f1 = *(const float4*)(src + 4);
        u16x8 o;
        o[0]=f2bf(f0.x); o[1]=f2bf(f0.y); o[2]=f2bf(f0.z); o[3]=f2bf(f0.w);
        o[4]=f2bf(f1.x); o[5]=f2bf(f1.y); o[6]=f2bf(f1.z); o[7]=f2bf(f1.w);
        *(u16x8*)(Bp + (long)blk * 512 + l * 8) = o;
    }
    if (id < 2560) {
        int row = (int)id;
        int g = row >> 9, j = row & 511;
        float b;
        if (g == 4) b = be[j];
        else {
            const float* bx = (g == 0) ? bxi : (g == 1) ? bxf : (g == 2) ? bxc : bxo;
            const float* bh = (g == 0) ? bhi : (g == 1) ? bhf : (g == 2) ? bhc : bho;
            b = bx[j] + bh[j];
        }
        bias[row] = b;
    }
}

// ---- fused GEMM: NO LDS, NO BARRIERS. All operands global->VGPR, frag-linear. ----
// Per wave per tile: 4 A loads + 5 B loads (1KB coalesced units) + 20 MFMA.
// Double-banked P/Q; loads for t+2 issued after MFMA(t) -> 2-tile vmcnt slack
// (compiler emits counted vmcnt before first use). 12 free-running waves/CU.

#define MF(a, b, c) __builtin_amdgcn_mfma_f32_16x16x32_bf16(a, b, c, 0, 0, 0)

#define LDA4(S, T) do { \
    a##S##0 = *(const bf16x8*)(asrc + (T) * 4096 + 0 * 512); \
    a##S##1 = *(const bf16x8*)(asrc + (T) * 4096 + 1 * 512); \
    a##S##2 = *(const bf16x8*)(asrc + (T) * 4096 + 2 * 512); \
    a##S##3 = *(const bf16x8*)(asrc + (T) * 4096 + 3 * 512); \
} while (0)

#define LDB5(S, T) do { \
    b##S##0 = *(const bf16x8*)(bsrc + (T) * 512 + 0 * 16384); \
    b##S##1 = *(const bf16x8*)(bsrc + (T) * 512 + 1 * 16384); \
    b##S##2 = *(const bf16x8*)(bsrc + (T) * 512 + 2 * 16384); \
    b##S##3 = *(const bf16x8*)(bsrc + (T) * 512 + 3 * 16384); \
    b##S##4 = *(const bf16x8*)(bsrc + (T) * 512 + 4 * 16384); \
} while (0)

#define MF4(S, BQ, G) \
    acc[G][0] = MF(a##S##0, BQ, acc[G][0]); \
    acc[G][1] = MF(a##S##1, BQ, acc[G][1]); \
    acc[G][2] = MF(a##S##2, BQ, acc[G][2]); \
    acc[G][3] = MF(a##S##3, BQ, acc[G][3]);

#define MFMA20(S) do { \
    MF4(S, b##S##0, 0) MF4(S, b##S##1, 1) MF4(S, b##S##2, 2) \
    MF4(S, b##S##3, 3) MF4(S, b##S##4, 4) \
} while (0)

__global__ __launch_bounds__(256, 3)
void xlstm_gemm(const unsigned short* __restrict__ Apk,
                const unsigned short* __restrict__ Bp,
                const float* __restrict__ bias,
                const float* __restrict__ c_prev,
                float* __restrict__ out) {
    const int tid  = threadIdx.x;
    const int wid  = tid >> 6;
    const int lane = tid & 63;
    const int wm   = wid >> 1;    // 0..1 : M half (64 rows)
    const int wj   = wid & 1;     // 0..1 : j half (16 cols)
    const int fr   = lane & 15;
    const int q    = lane >> 4;

    // XCD swizzle: concurrent same-XCD wgs share jblk (B panel L2-resident).
    // bijective: (xcd, oid) -> jblk = oid>>4 (0..15), mblk = (oid&15)*8 + xcd (0..127)
    const int orig = blockIdx.x;
    const int xcd  = orig & 7;
    const int oid  = orig >> 3;           // 0..255
    const int jblk = oid >> 4;            // 0..15
    const int mblk = (oid & 15) * 8 + xcd;// 0..127
    const long brow = (long)mblk * BM;
    const int  bcol = jblk * BNJ;

    f32x4 acc[5][4];
#pragma unroll
    for (int g = 0; g < 5; ++g)
#pragma unroll
        for (int m = 0; m < 4; ++m)
#pragma unroll
            for (int r = 0; r < 4; ++r) acc[g][m][r] = 0.f;

    // named operand banks (rule 20: no runtime-indexed reg arrays)
    bf16x8 aP0, aP1, aP2, aP3, bP0, bP1, bP2, bP3, bP4;
    bf16x8 aQ0, aQ1, aQ2, aQ3, bQ0, bQ1, bQ2, bQ3, bQ4;

    // A: units (mblk*32 + t)*8 + wm*4 + i ; lane's 16B at lane*8 elems
    const unsigned short* asrc = Apk + (long)mblk * 131072 + wm * 2048 + lane * 8;
    // B: jgrp = jblk*2 + wj; unit g*16384 + t*512 elems
    const unsigned short* bsrc = Bp + (long)(jblk * 2 + wj) * 81920 + lane * 8;

    // ---- prologue: fill both banks ----
    LDA4(P, 0); LDB5(P, 0);
    LDA4(Q, 1); LDB5(Q, 1);

    // ---- main loop: free-running, compiler-counted vmcnt, 2-tile load slack ----
    for (int t = 0; t < 28; t += 2) {
        MFMA20(P);
        LDA4(P, t + 2); LDB5(P, t + 2);
        MFMA20(Q);
        LDA4(Q, t + 3); LDB5(Q, t + 3);
    }
    MFMA20(P);                 // tile 28
    LDA4(P, 30); LDB5(P, 30);
    MFMA20(Q);                 // tile 29
    LDA4(Q, 31); LDB5(Q, 31);
    MFMA20(P);                 // tile 30
    MFMA20(Q);                 // tile 31

    // ---------------- epilogue (fused, in-register) ----------------
    const int j = bcol + wj * 16 + fr;
    const float bi_ = bias[j];
    const float bf_ = bias[512 + j];
    const float bc_ = bias[1024 + j];
    const float bo_ = bias[1536 + j];
    const float be_ = bias[2048 + j];
    const long mbase = brow + wm * 64 + (q << 2);
#pragma unroll
    for (int m = 0; m < 4; ++m) {
#pragma unroll
        for (int r = 0; r < 4; ++r) {
            long row = mbase + m * 16 + r;
            float gi = acc[0][m][r] + bi_;
            float gf = acc[1][m][r] + bf_;
            float gc = acc[2][m][r] + bc_;
            float go = acc[3][m][r] + bo_;
            float ge = acc[4][m][r] + be_;
            float iv = fast_sigmoid(gi);
            float fv = fast_sigmoid(gf);
            float gv = fast_tanh(gc);
            float ov = fast_sigmoid(go);
            float ef = __expf(fast_tanh(ge));
            float cp = c_prev[row * 512 + j];
            float cv = fv * cp + iv * gv;
            float hv = ov * fast_tanh(cv) * ef;
            out[row * 512 + j] = hv;
            out[(long)Bsz * 512 + row * 512 + j] = cv;
        }
    }
}

extern "C" void kernel_launch(void* const* d_in, const int* in_sizes, int n_in,
                              void* d_out, int out_size, void* d_ws, size_t ws_size,
                              hipStream_t stream) {
    const float* x      = (const float*)d_in[0];
    const float* h_prev = (const float*)d_in[1];
    const float* c_prev = (const float*)d_in[2];
    const float* Wxi = (const float*)d_in[3];
    const float* bxi = (const float*)d_in[4];
    const float* Whi = (const float*)d_in[5];
    const float* bhi = (const float*)d_in[6];
    const float* Wxf = (const float*)d_in[7];
    const float* bxf = (const float*)d_in[8];
    const float* Whf = (const float*)d_in[9];
    const float* bhf = (const float*)d_in[10];
    const float* Wxc = (const float*)d_in[11];
    const float* bxc = (const float*)d_in[12];
    const float* Whc = (const float*)d_in[13];
    const float* bhc = (const float*)d_in[14];
    const float* Wxo = (const float*)d_in[15];
    const float* bxo = (const float*)d_in[16];
    const float* Who = (const float*)d_in[17];
    const float* bho = (const float*)d_in[18];
    const float* We  = (const float*)d_in[19];
    const float* be  = (const float*)d_in[20];

    unsigned short* Abf  = (unsigned short*)d_ws;                        // 33,554,432 B
    unsigned short* Bp   = (unsigned short*)((char*)d_ws + 33554432);    //  5,242,880 B
    float*          bias = (float*)((char*)d_ws + 33554432 + 5242880);   //     10,240 B

    pack_A<<<2048, 256, 0, stream>>>(x, h_prev, Abf);
    pack_B<<<1280, 256, 0, stream>>>(Wxi, Whi, Wxf, Whf, Wxc, Whc, Wxo, Who, We,
                                     bxi, bhi, bxf, bhf, bxc, bhc, bxo, bho, be,
                                     Bp, bias);
    xlstm_gemm<<<2048, 256, 0, stream>>>(Abf, Bp, bias, c_prev, (float*)d_out);
}

// Round 14
// 121.516 us; speedup vs baseline: 1.3515x; 1.3515x over previous
//
#include <hip/hip_runtime.h>
#include <stdint.h>

#define Bsz 16384
#define Hh  512
#define Kd  1024      // I + H
#define BM  256       // M rows per workgroup
#define BNJ 64        // j columns per workgroup (x5 gates)
#define NH  32        // half-tiles (BK=32 each)

// LDS: 4 half-tile buffers x 36 KB (A 16KB + B 20KB) = 144 KB -> 1 wg/CU
#define HBUF 36864

typedef __attribute__((ext_vector_type(8))) short bf16x8;
typedef __attribute__((ext_vector_type(4))) float f32x4;
typedef __attribute__((ext_vector_type(8))) unsigned short u16x8;

__device__ __forceinline__ unsigned short f2bf(float f) {
    union { float f; unsigned u; } v; v.f = f;
    unsigned u = v.u;
    return (unsigned short)((u + 0x7fffu + ((u >> 16) & 1u)) >> 16);
}
__device__ __forceinline__ float fast_tanh(float x) {
    float e = __expf(2.f * x);
    return (e - 1.f) / (e + 1.f);
}
__device__ __forceinline__ float fast_sigmoid(float x) {
    return 1.f / (1.f + __expf(-x));
}

// ---- pack A fragment-linear (R12-proven): unit blk = (mblk*32 + t)*8 + u ----
// elem blk*512 + l*8 + e = A[mblk*128 + u*16 + (l&15)][t*32 + (l>>4)*8 + e]
__global__ void pack_A(const float* __restrict__ x, const float* __restrict__ h,
                       unsigned short* __restrict__ A) {
    const long total = (long)Bsz * Kd / 8;   // 2,097,152 units of 8
    for (long i = (long)blockIdx.x * blockDim.x + threadIdx.x; i < total;
         i += (long)gridDim.x * blockDim.x) {
        int  l    = (int)(i & 63);
        long blk  = i >> 6;
        int  u    = (int)(blk & 7);
        int  t    = (int)((blk >> 3) & 31);
        long mblk = blk >> 8;
        long row  = mblk * 128 + u * 16 + (l & 15);
        int  k0   = t * 32 + ((l >> 4) << 3);
        const float* src = (k0 < 512) ? (x + row * 512 + k0)
                                      : (h + row * 512 + (k0 - 512));
        float4 f0 = *(const float4*)(src);
        float4 f1 = *(const float4*)(src + 4);
        u16x8 o;
        o[0]=f2bf(f0.x); o[1]=f2bf(f0.y); o[2]=f2bf(f0.z); o[3]=f2bf(f0.w);
        o[4]=f2bf(f1.x); o[5]=f2bf(f1.y); o[6]=f2bf(f1.z); o[7]=f2bf(f1.w);
        *(u16x8*)(A + (i << 3)) = o;
    }
}

// ---- pack B fragment-linear (proven): ----
// elem jgrp*81920 + g*16384 + h*512 + l*8 + e
//  = W[g][ j = jgrp*16 + (l&15) ][ k = h*32 + (l>>4)*8 + e ]
__global__ void pack_B(const float* __restrict__ Wxi, const float* __restrict__ Whi,
                       const float* __restrict__ Wxf, const float* __restrict__ Whf,
                       const float* __restrict__ Wxc, const float* __restrict__ Whc,
                       const float* __restrict__ Wxo, const float* __restrict__ Who,
                       const float* __restrict__ We,
                       const float* __restrict__ bxi, const float* __restrict__ bhi,
                       const float* __restrict__ bxf, const float* __restrict__ bhf,
                       const float* __restrict__ bxc, const float* __restrict__ bhc,
                       const float* __restrict__ bxo, const float* __restrict__ bho,
                       const float* __restrict__ be,
                       unsigned short* __restrict__ Bp, float* __restrict__ bias) {
    const long id = (long)blockIdx.x * blockDim.x + threadIdx.x;  // 327680 total
    if (id < 327680) {
        int blk = (int)(id >> 6);
        int l   = (int)(id & 63);
        int kh  = blk & 1;
        int kt  = (blk >> 1) & 15;
        int rest = blk >> 5;
        int g    = rest % 5;
        int jgrp = rest / 5;
        int j  = jgrp * 16 + (l & 15);
        int k0 = kt * 64 + kh * 32 + ((l >> 4) << 3);
        const float* src;
        if (g == 4) {
            src = We + (long)j * 1024 + k0;
        } else {
            const float* Wx = (g == 0) ? Wxi : (g == 1) ? Wxf : (g == 2) ? Wxc : Wxo;
            const float* Wh = (g == 0) ? Whi : (g == 1) ? Whf : (g == 2) ? Whc : Who;
            src = (k0 < 512) ? (Wx + (long)j * 512 + k0)
                             : (Wh + (long)j * 512 + (k0 - 512));
        }
        float4 f0 = *(const float4*)(src);
        float4 f1 = *(const float4*)(src + 4);
        u16x8 o;
        o[0]=f2bf(f0.x); o[1]=f2bf(f0.y); o[2]=f2bf(f0.z); o[3]=f2bf(f0.w);
        o[4]=f2bf(f1.x); o[5]=f2bf(f1.y); o[6]=f2bf(f1.z); o[7]=f2bf(f1.w);
        *(u16x8*)(Bp + (long)blk * 512 + l * 8) = o;
    }
    if (id < 2560) {
        int row = (int)id;
        int g = row >> 9, j = row & 511;
        float b;
        if (g == 4) b = be[j];
        else {
            const float* bx = (g == 0) ? bxi : (g == 1) ? bxf : (g == 2) ? bxc : bxo;
            const float* bh = (g == 0) ? bhi : (g == 1) ? bhf : (g == 2) ? bhc : bho;
            b = bx[j] + bh[j];
        }
        bias[row] = b;
    }
}

// ---- fused GEMM: 256x(64x5) tile, 2-phase/half-tile, 4 bufs, vmcnt(10), 1 wg/CU ----
#define GL16(g, l) __builtin_amdgcn_global_load_lds( \
    (const __attribute__((address_space(1))) unsigned int*)(g), \
    (__attribute__((address_space(3))) unsigned int*)(l), 16, 0, 0)

#define VM_I(n)    asm volatile("s_waitcnt vmcnt(" #n ")" ::: "memory")
#define VM(n)      VM_I(n)
#define LGKM0()    asm volatile("s_waitcnt lgkmcnt(0)" ::: "memory")
#define BARRIER()  asm volatile("s_barrier" ::: "memory")
#define SCHED0()   __builtin_amdgcn_sched_barrier(0)

#define MF(a, b, c) __builtin_amdgcn_mfma_f32_16x16x32_bf16(a, b, c, 0, 0, 0)

#define RDA4(BO) do { \
    af0 = *(const bf16x8*)(lds_raw + (BO) + aoff + 0 * 1024); \
    af1 = *(const bf16x8*)(lds_raw + (BO) + aoff + 1 * 1024); \
    af2 = *(const bf16x8*)(lds_raw + (BO) + aoff + 2 * 1024); \
    af3 = *(const bf16x8*)(lds_raw + (BO) + aoff + 3 * 1024); \
} while (0)

#define RDB5(BO, JF) do { \
    bq0 = *(const bf16x8*)(lds_raw + (BO) + boff + (JF) * 5120 + 0 * 1024); \
    bq1 = *(const bf16x8*)(lds_raw + (BO) + boff + (JF) * 5120 + 1 * 1024); \
    bq2 = *(const bf16x8*)(lds_raw + (BO) + boff + (JF) * 5120 + 2 * 1024); \
    bq3 = *(const bf16x8*)(lds_raw + (BO) + boff + (JF) * 5120 + 3 * 1024); \
    bq4 = *(const bf16x8*)(lds_raw + (BO) + boff + (JF) * 5120 + 4 * 1024); \
} while (0)

#define MF4(JF, BQ, G) \
    acc[G][JF][0] = MF(af0, BQ, acc[G][JF][0]); \
    acc[G][JF][1] = MF(af1, BQ, acc[G][JF][1]); \
    acc[G][JF][2] = MF(af2, BQ, acc[G][JF][2]); \
    acc[G][JF][3] = MF(af3, BQ, acc[G][JF][3]);

#define MFMA20(JF) do { \
    __builtin_amdgcn_s_setprio(1); \
    MF4(JF, bq0, 0) MF4(JF, bq1, 1) MF4(JF, bq2, 2) MF4(JF, bq3, 3) MF4(JF, bq4, 4) \
    __builtin_amdgcn_s_setprio(0); \
} while (0)

// one staging GL16: slot s of half-tile H into buffer byte offset SB
#define SG(SB, H, s) GL16(sg##s + (long)(H) * st##s, lds_raw + (SB) + ld##s)

// half-tile T: reads buf BO, stages T+3 into SB (if STG), vmcnt per DOVM/WN
#define STEP(T, BO, SB, STG, DOVM, WN) do { \
    /* phase 0 (jf=0): A4+B5 reads, 3 staging issues */ \
    RDA4(BO); RDB5(BO, 0); \
    if (STG) { SG(SB, (T) + 3, 0); SG(SB, (T) + 3, 1); SG(SB, (T) + 3, 2); } \
    BARRIER(); LGKM0(); SCHED0(); \
    MFMA20(0); \
    BARRIER(); \
    /* phase 1 (jf=1): B5 reads, 2 staging issues, counted vmcnt */ \
    RDB5(BO, 1); \
    if (STG) { SG(SB, (T) + 3, 3); SG(SB, (T) + 3, 4); } \
    BARRIER(); LGKM0(); SCHED0(); \
    MFMA20(1); \
    if (DOVM) VM(WN); \
    BARRIER(); \
} while (0)

__global__ __launch_bounds__(512, 2)
void xlstm_gemm(const unsigned short* __restrict__ Apk,
                const unsigned short* __restrict__ Bp,
                const float* __restrict__ bias,
                const float* __restrict__ c_prev,
                float* __restrict__ out) {
    __shared__ __align__(16) unsigned char lds_raw[4 * HBUF];  // 144 KB

    const int tid  = threadIdx.x;
    const int wid  = tid >> 6;
    const int lane = tid & 63;
    const int wm   = wid >> 1;    // 0..3 : 64-row group
    const int wj   = wid & 1;     // 0..1 : 32-col group
    const int fr   = lane & 15;
    const int q    = lane >> 4;

    // XCD ownership swizzle: Jblk = xcd (B panel 640 KB L2-resident), Mblk = seq
    const int orig = blockIdx.x;           // 0..511
    const int Jblk = orig & 7;             // 0..7
    const int Mblk = orig >> 3;            // 0..63
    const long brow = (long)Mblk * BM;
    const int  bcol = Jblk * BNJ;

    f32x4 acc[5][2][4];
#pragma unroll
    for (int g = 0; g < 5; ++g)
#pragma unroll
        for (int jf = 0; jf < 2; ++jf)
#pragma unroll
            for (int m = 0; m < 4; ++m)
#pragma unroll
                for (int r = 0; r < 4; ++r) acc[g][jf][m][r] = 0.f;

    bf16x8 af0, af1, af2, af3;
    bf16x8 bq0, bq1, bq2, bq3, bq4;

    // read-side byte offsets within a buffer
    const int aoff = wm * 4096 + lane * 16;           // A unit wm*4+m @ (wm*4+m)*1024
    const int boff = 16384 + wj * 10240 + lane * 16;  // B unit (wj*2+jf)*5+g

    // ---- staging slots: 5 per thread; chunk c -> (src ptr, per-h stride, lds off) ----
    const unsigned short *sg0, *sg1, *sg2, *sg3, *sg4;
    int st0, st1, st2, st3, st4, ld0, ld1, ld2, ld3, ld4;
#define SLOT_INIT(s) do { \
    int c_ = ((s) < 4) ? (tid + (s) * 512) : (2048 + (tid & 255)); \
    int l_ = c_ & 63; \
    if (c_ < 1024) { \
        int u_ = c_ >> 6; \
        sg##s = Apk + ((long)(Mblk * 2 + (u_ >> 3)) * 256 + (u_ & 7)) * 512 + l_ * 8; \
        st##s = 4096; \
    } else { \
        int bu_ = (c_ - 1024) >> 6; \
        int wjf_ = bu_ / 5; int g_ = bu_ - 5 * wjf_; \
        sg##s = Bp + (long)(Jblk * 4 + wjf_) * 81920 + g_ * 16384 + l_ * 8; \
        st##s = 512; \
    } \
    ld##s = c_ * 16; \
} while (0)
    SLOT_INIT(0); SLOT_INIT(1); SLOT_INIT(2); SLOT_INIT(3); SLOT_INIT(4);
#undef SLOT_INIT

    // ---- prologue: stage half-tiles 0,1,2 -> bufs 0,1,2; certify 0 ----
    SG(0 * HBUF, 0, 0); SG(0 * HBUF, 0, 1); SG(0 * HBUF, 0, 2); SG(0 * HBUF, 0, 3); SG(0 * HBUF, 0, 4);
    SG(1 * HBUF, 1, 0); SG(1 * HBUF, 1, 1); SG(1 * HBUF, 1, 2); SG(1 * HBUF, 1, 3); SG(1 * HBUF, 1, 4);
    SG(2 * HBUF, 2, 0); SG(2 * HBUF, 2, 1); SG(2 * HBUF, 2, 2); SG(2 * HBUF, 2, 3); SG(2 * HBUF, 2, 4);
    VM(10);          // h0's 5 done; h1,h2 in flight
    BARRIER();

    // ---- main loop: half-tile h reads buf h&3, stages h+3 into (h+3)&3 ----
    for (int h = 0; h < 28; h += 4) {
        STEP(h + 0, 0 * HBUF, 3 * HBUF, 1, 1, 10);
        STEP(h + 1, 1 * HBUF, 0 * HBUF, 1, 1, 10);
        STEP(h + 2, 2 * HBUF, 1 * HBUF, 1, 1, 10);
        STEP(h + 3, 3 * HBUF, 2 * HBUF, 1, 1, 10);
    }
    STEP(28, 0 * HBUF, 3 * HBUF, 1, 1, 10);  // stages 31; certifies 29
    STEP(29, 1 * HBUF, 0,        0, 1, 5);   // certifies 30
    STEP(30, 2 * HBUF, 0,        0, 1, 0);   // certifies 31
    STEP(31, 3 * HBUF, 0,        0, 0, 0);

    // ---------------- epilogue (fused, in-register) ----------------
    const long mbase = brow + wm * 64 + (q << 2);
#pragma unroll
    for (int jf = 0; jf < 2; ++jf) {
        const int j = bcol + wj * 32 + jf * 16 + fr;
        const float bi_ = bias[j];
        const float bf_ = bias[512 + j];
        const float bc_ = bias[1024 + j];
        const float bo_ = bias[1536 + j];
        const float be_ = bias[2048 + j];
#pragma unroll
        for (int m = 0; m < 4; ++m) {
#pragma unroll
            for (int r = 0; r < 4; ++r) {
                long row = mbase + m * 16 + r;
                float gi = acc[0][jf][m][r] + bi_;
                float gf = acc[1][jf][m][r] + bf_;
                float gc = acc[2][jf][m][r] + bc_;
                float go = acc[3][jf][m][r] + bo_;
                float ge = acc[4][jf][m][r] + be_;
                float iv = fast_sigmoid(gi);
                float fv = fast_sigmoid(gf);
                float gv = fast_tanh(gc);
                float ov = fast_sigmoid(go);
                float ef = __expf(fast_tanh(ge));
                float cp = c_prev[row * 512 + j];
                float cv = fv * cp + iv * gv;
                float hv = ov * fast_tanh(cv) * ef;
                out[row * 512 + j] = hv;
                out[(long)Bsz * 512 + row * 512 + j] = cv;
            }
        }
    }
}

extern "C" void kernel_launch(void* const* d_in, const int* in_sizes, int n_in,
                              void* d_out, int out_size, void* d_ws, size_t ws_size,
                              hipStream_t stream) {
    const float* x      = (const float*)d_in[0];
    const float* h_prev = (const float*)d_in[1];
    const float* c_prev = (const float*)d_in[2];
    const float* Wxi = (const float*)d_in[3];
    const float* bxi = (const float*)d_in[4];
    const float* Whi = (const float*)d_in[5];
    const float* bhi = (const float*)d_in[6];
    const float* Wxf = (const float*)d_in[7];
    const float* bxf = (const float*)d_in[8];
    const float* Whf = (const float*)d_in[9];
    const float* bhf = (const float*)d_in[10];
    const float* Wxc = (const float*)d_in[11];
    const float* bxc = (const float*)d_in[12];
    const float* Whc = (const float*)d_in[13];
    const float* bhc = (const float*)d_in[14];
    const float* Wxo = (const float*)d_in[15];
    const float* bxo = (const float*)d_in[16];
    const float* Who = (const float*)d_in[17];
    const float* bho = (const float*)d_in[18];
    const float* We  = (const float*)d_in[19];
    const float* be  = (const float*)d_in[20];

    unsigned short* Abf  = (unsigned short*)d_ws;                        // 33,554,432 B
    unsigned short* Bp   = (unsigned short*)((char*)d_ws + 33554432);    //  5,242,880 B
    float*          bias = (float*)((char*)d_ws + 33554432 + 5242880);   //     10,240 B

    pack_A<<<2048, 256, 0, stream>>>(x, h_prev, Abf);
    pack_B<<<1280, 256, 0, stream>>>(Wxi, Whi, Wxf, Whf, Wxc, Whc, Wxo, Who, We,
                                     bxi, bhi, bxf, bhf, bxc, bhc, bxo, bho, be,
                                     Bp, bias);
    xlstm_gemm<<<512, 512, 0, stream>>>(Abf, Bp, bias, c_prev, (float*)d_out);
}